// Round 1
// baseline (5569.741 us; speedup 1.0000x reference)
//
#include <hip/hip_runtime.h>
#include <hip/hip_bf16.h>

#define H 256
#define T_STEPS 128
#define B_BATCH 256

__device__ __forceinline__ float sigmoidf_(float x) { return 1.0f / (1.0f + expf(-x)); }

// ---------------- prep kernels (run once per launch, tiny) ----------------

// Weff[i][j] = sum_d W1[d][i] * W2[j][d];  beff[j] = b2[j] + sum_d b1[d]*W2[j][d]
__global__ void prep_weff(const float* __restrict__ W1, const float* __restrict__ W2,
                          const float* __restrict__ b1, const float* __restrict__ b2,
                          float* __restrict__ Weff, float* __restrict__ beff) {
    int i = blockIdx.x;    // input index of Weff row
    int j = threadIdx.x;   // output index (column)
    const float* w2row = W2 + j * H;  // W2[j][d], contiguous per thread
    float acc = 0.f;
    for (int d = 0; d < H; ++d) acc += W1[d * H + i] * w2row[d];
    Weff[i * H + j] = acc;
    if (i == 0) {
        float bacc = b2[j];
        for (int d = 0; d < H; ++d) bacc += b1[d] * w2row[d];
        beff[j] = bacc;
    }
}

// WhhT[i][r] = W_hh[r][i]   (i in [0,256), r in [0,768))
__global__ void prep_whht(const float* __restrict__ Whh, float* __restrict__ WhhT) {
    int idx = blockIdx.x * blockDim.x + threadIdx.x;  // 196608 total
    int i = idx / 768;
    int r = idx - i * 768;
    WhhT[idx] = Whh[r * H + i];
}

// wo[i] = sum_d Wo1[d][i]*Wo2[d];  bo = bo2[0] + sum_d bo1[d]*Wo2[d]
__global__ void prep_wo(const float* __restrict__ Wo1, const float* __restrict__ Wo2,
                        const float* __restrict__ bo1, const float* __restrict__ bo2,
                        float* __restrict__ wo, float* __restrict__ bo) {
    int i = threadIdx.x;  // 256 threads
    float acc = 0.f;
    for (int d = 0; d < H; ++d) acc += Wo1[d * H + i] * Wo2[d];
    wo[i] = acc;
    float p = bo1[i] * Wo2[i];
    __shared__ float red[4];
    for (int off = 32; off > 0; off >>= 1) p += __shfl_down(p, off);
    if ((i & 63) == 0) red[i >> 6] = p;
    __syncthreads();
    if (i == 0) bo[0] = red[0] + red[1] + red[2] + red[3] + bo2[0];
}

// ---------------- main scan kernel: 1 block per batch row ----------------

__device__ __forceinline__ float feval(float v, float* xs, const float* __restrict__ wcol,
                                       float be, int j) {
    __syncthreads();          // previous consumers of xs are done
    xs[j] = v;
    __syncthreads();
    float acc = be;
    #pragma unroll 2
    for (int i = 0; i < H; i += 8) {
        float4 xa = *(const float4*)(xs + i);
        float4 xb = *(const float4*)(xs + i + 4);
        float w0 = wcol[(i + 0) * H], w1 = wcol[(i + 1) * H];
        float w2 = wcol[(i + 2) * H], w3 = wcol[(i + 3) * H];
        float w4 = wcol[(i + 4) * H], w5 = wcol[(i + 5) * H];
        float w6 = wcol[(i + 6) * H], w7 = wcol[(i + 7) * H];
        acc += xa.x * w0 + xa.y * w1 + xa.z * w2 + xa.w * w3;
        acc += xb.x * w4 + xb.y * w5 + xb.z * w6 + xb.w * w7;
    }
    return tanhf(acc);
}

__launch_bounds__(256)
__global__ void ode_rnn_main(
    const float* __restrict__ b_in, const float* __restrict__ m_in,
    const float* __restrict__ trm_in, const float* __restrict__ tem_in,
    const float* __restrict__ h0,
    const float* __restrict__ Weff, const float* __restrict__ beff,
    const float* __restrict__ WhhT,
    const float* __restrict__ W_ih, const float* __restrict__ b_ih,
    const float* __restrict__ b_hh,
    const float* __restrict__ wo, const float* __restrict__ bo_p,
    float* __restrict__ out)
{
    const int bb = blockIdx.x;   // batch row
    const int j  = threadIdx.x;  // hidden index owned by this thread

    __shared__ __align__(16) float xs[H];
    __shared__ float red[4];
    __shared__ float out_sh;

    float h = h0[bb * H + j];

    const float bih_r = b_ih[j], bih_z = b_ih[H + j], bih_n = b_ih[2 * H + j];
    const float bhh_r = b_hh[j], bhh_z = b_hh[H + j], bhh_n = b_hh[2 * H + j];
    const float wih_r = W_ih[j], wih_z = W_ih[H + j], wih_n = W_ih[2 * H + j];
    const float be  = beff[j];
    const float woj = wo[j];
    const float bo  = bo_p[0];
    const float* wcol = Weff + j;
    const float* wh   = WhhT + j;

    float tprev = 0.f;
    for (int t = 0; t < T_STEPS; ++t) {
        float t1 = b_in[2 * t];           // times are broadcast across batch; row 0
        float dt = (t1 - tprev) * 0.5f;   // per-substep dt, N_SUB=2
        tprev = t1;

        // ---- RK4 x 2 substeps ----
        #pragma unroll 1
        for (int s = 0; s < 2; ++s) {
            float k1 = feval(h, xs, wcol, be, j);
            float k2 = feval(fmaf(0.5f * dt, k1, h), xs, wcol, be, j);
            float k3 = feval(fmaf(0.5f * dt, k2, h), xs, wcol, be, j);
            float k4 = feval(fmaf(dt, k3, h), xs, wcol, be, j);
            h = h + (dt * (1.f / 6.f)) * (k1 + 2.f * k2 + 2.f * k3 + k4);
        }

        // ---- stage hp for the GRU matvec ----
        __syncthreads();
        xs[j] = h;
        __syncthreads();

        // ---- out = tanh(hp . wo + bo) : block reduction ----
        float p = h * woj;
        for (int off = 32; off > 0; off >>= 1) p += __shfl_down(p, off);
        if ((j & 63) == 0) red[j >> 6] = p;
        __syncthreads();
        if (j == 0) out_sh = tanhf(red[0] + red[1] + red[2] + red[3] + bo);
        __syncthreads();
        float outv = out_sh;

        // ---- gh = hp @ W_hh^T (shared by both GRUs) ----
        float ghr = bhh_r, ghz = bhh_z, ghn = bhh_n;
        #pragma unroll 2
        for (int i = 0; i < H; i += 2) {
            float x0 = xs[i], x1 = xs[i + 1];
            ghr += x0 * wh[i * 768]       + x1 * wh[(i + 1) * 768];
            ghz += x0 * wh[i * 768 + 256] + x1 * wh[(i + 1) * 768 + 256];
            ghn += x0 * wh[i * 768 + 512] + x1 * wh[(i + 1) * 768 + 512];
        }

        // ---- gates ----
        int bt = bb * T_STEPS + t;
        float bv  = b_in[2 * bt + 1];
        float trm = trm_in[bt], tem = tem_in[bt], mv = m_in[bt];
        float x1v = bv * trm;
        float x2v = outv * tem;

        float r1 = sigmoidf_(fmaf(x1v, wih_r, bih_r) + ghr);
        float z1 = sigmoidf_(fmaf(x1v, wih_z, bih_z) + ghz);
        float n1 = tanhf(fmaf(x1v, wih_n, bih_n) + r1 * ghn);
        float h1 = (1.f - z1) * n1 + z1 * h;

        float r2 = sigmoidf_(fmaf(x2v, wih_r, bih_r) + ghr);
        float z2 = sigmoidf_(fmaf(x2v, wih_z, bih_z) + ghz);
        float n2 = tanhf(fmaf(x2v, wih_n, bih_n) + r2 * ghn);
        float h2 = (1.f - z2) * n2 + z2 * h;

        if (j == 0) out[bt] = outv;
        h = trm * h1 + tem * h2 + (1.f - mv) * h;
    }
}

// ---------------- launcher ----------------

extern "C" void kernel_launch(void* const* d_in, const int* in_sizes, int n_in,
                              void* d_out, int out_size, void* d_ws, size_t ws_size,
                              hipStream_t stream) {
    const float* b_in = (const float*)d_in[0];
    const float* m_in = (const float*)d_in[1];
    const float* trm  = (const float*)d_in[2];
    const float* tem  = (const float*)d_in[3];
    const float* h0   = (const float*)d_in[4];
    const float* W1   = (const float*)d_in[5];
    const float* b1   = (const float*)d_in[6];
    const float* W2   = (const float*)d_in[7];
    const float* b2   = (const float*)d_in[8];
    const float* W_ih = (const float*)d_in[9];
    const float* W_hh = (const float*)d_in[10];
    const float* b_ih = (const float*)d_in[11];
    const float* b_hh = (const float*)d_in[12];
    const float* Wo1  = (const float*)d_in[13];
    const float* bo1  = (const float*)d_in[14];
    const float* Wo2  = (const float*)d_in[15];
    const float* bo2  = (const float*)d_in[16];

    float* ws   = (float*)d_ws;
    float* Weff = ws;             // 65536
    float* beff = Weff + 65536;   // 256
    float* WhhT = beff + 256;     // 196608
    float* wo   = WhhT + 196608;  // 256
    float* bo   = wo + 256;       // 1

    prep_weff<<<256, 256, 0, stream>>>(W1, W2, b1, b2, Weff, beff);
    prep_whht<<<192, 1024, 0, stream>>>(W_hh, WhhT);
    prep_wo<<<1, 256, 0, stream>>>(Wo1, Wo2, bo1, bo2, wo, bo);

    ode_rnn_main<<<B_BATCH, 256, 0, stream>>>(b_in, m_in, trm, tem, h0,
                                              Weff, beff, WhhT,
                                              W_ih, b_ih, b_hh, wo, bo,
                                              (float*)d_out);
}